// Round 3
// baseline (113.163 us; speedup 1.0000x reference)
//
#include <hip/hip_runtime.h>
#include <math.h>

#define NSEG 20001      // I_DIM + 1 segments / items
#define EMB  128
#define NE   640000

#define SCALE_BLOCKS 313         // ceil(NSEG/64) : 64 rows per block
#define BOUNDS_BLOCKS 2500       // NE/256 exact
#define TPAD 76                  // transposed emb tile row stride (floats):
                                 //  %4==0 -> 16B-aligned b128 reads
                                 //  %32==12, gcd(12,32)=4 -> fill writes only 4-way

__device__ __forceinline__ float dot4(float4 a, float4 b) {
    return a.x*b.x + a.y*b.y + a.z*b.z + a.w*b.w;
}

#define FMA4(acc, s, b) { acc.x += (s)*(b).x; acc.y += (s)*(b).y; acc.z += (s)*(b).z; acc.w += (s)*(b).w; }

__device__ __forceinline__ unsigned f2bf(float x) {
    unsigned u = __float_as_uint(x);
    return (u + 0x7fffu + ((u >> 16) & 1u)) >> 16;   // round-nearest-even
}

// Fused prep:
//  blocks [0, SCALE_BLOCKS): item_scaled(bf16 tab) + a_src/a_dst.
//    64 rows/block. Thread tile reshaped 4rx8c -> 8r x 4c and emb tile stored
//    TRANSPOSED [k][row]: per wave per k the LDS pipe now serves
//    1x ds_read_b128 (W) + 2x ds_read_b128 (A, 8 consecutive rows, k-uniform
//    broadcast) = 36 cyc instead of 47, for the same 32 lane-fmacs.
//    The k-loop is LDS-issue-bound (LDS shared by 4 SIMDs), so cycles/row/k
//    drop ~2x (11.8 -> 6). W staged in LDS 32-k chunks (round-2 win, kept).
//  blocks [SCALE_BLOCKS, +BOUNDS_BLOCKS): segment bounds + dst compaction.
__global__ __launch_bounds__(256) void prep_kernel(
    const float* __restrict__ emb, const float* __restrict__ W,
    const float* __restrict__ bsc, const float* __restrict__ Watt,
    const int* __restrict__ edge,
    unsigned short* __restrict__ tab,       // bf16 item_scaled, NSEG x EMB
    float* __restrict__ a_src, float* __restrict__ a_dst,
    int* __restrict__ seg_start, int* __restrict__ dst)
{
    const int tid = threadIdx.x;
    if (blockIdx.x >= SCALE_BLOCKS) {
        // ---- bounds + dst-compaction ----
        int e = (blockIdx.x - SCALE_BLOCKS) * 256 + tid;
        int2 p = ((const int2*)edge)[e];            // coalesced 8B
        dst[e] = p.y;
        int sp = __shfl_up(p.x, 1);
        if ((tid & 63) == 0) sp = (e == 0) ? -1 : edge[2*e - 2];
        for (int t = sp + 1; t <= p.x; ++t) seg_start[t] = e;
        if (e == NE - 1) {
            for (int t = p.x + 1; t <= NSEG; ++t) seg_start[t] = NE;
        }
        return;
    }

    // ---- scale branch: 64 rows/block, transposed emb tile + W LDS chunks ----
    __shared__ __align__(16) float emb_t[EMB * TPAD];  // [k][row] 38.9 KB
    __shared__ __align__(16) float w_s[32 * EMB];      // 16.4 KB chunk
    const int r0 = blockIdx.x * 64;

    const float4* embg4 = (const float4*)emb;
    const int gmax = NSEG * 32 - 1;
    #pragma unroll
    for (int j = 0; j < 8; ++j) {
        int idx = tid + j * 256;            // 0..2047 tile float4 slots
        int row = idx >> 5, f4 = idx & 31;  // f4: which 4-k group
        int g = r0 * 32 + idx;
        float4 v = embg4[g <= gmax ? g : gmax];
        int k = f4 * 4;
        emb_t[(k+0)*TPAD + row] = v.x;      // 4-way bank aliasing max (TPAD=76)
        emb_t[(k+1)*TPAD + row] = v.y;
        emb_t[(k+2)*TPAD + row] = v.z;
        emb_t[(k+3)*TPAD + row] = v.w;
    }

    const int cg   = tid & 31;            // cols [4cg, 4cg+4)
    const int rowb = ((tid >> 6) << 4) + ((tid >> 5) & 1) * 8;  // 8 rows: rowb..rowb+7

    float4 acc[8] = {{0,0,0,0},{0,0,0,0},{0,0,0,0},{0,0,0,0},
                     {0,0,0,0},{0,0,0,0},{0,0,0,0},{0,0,0,0}};
    const float4* Wg4 = (const float4*)W;
    const float4* ws4 = (const float4*)w_s;

    for (int c = 0; c < 4; ++c) {
        __syncthreads();                    // chunk c-1 consumed; emb fill ordered
        #pragma unroll
        for (int j = 0; j < 4; ++j) {
            int idx = tid + j * 256;        // 1024 float4 slots of 32-row W chunk
            ((float4*)w_s)[idx] = Wg4[c * 1024 + idx];
        }
        __syncthreads();                    // chunk c ready

        #pragma unroll 4
        for (int kk = 0; kk < 32; ++kk) {
            const int k = c * 32 + kk;
            float4 w   = ws4[kk*32 + cg];                       // 16B, cols 4cg..
            float4 a03 = *(const float4*)&emb_t[k*TPAD + rowb];
            float4 a47 = *(const float4*)&emb_t[k*TPAD + rowb + 4];
            FMA4(acc[0], a03.x, w);
            FMA4(acc[1], a03.y, w);
            FMA4(acc[2], a03.z, w);
            FMA4(acc[3], a03.w, w);
            FMA4(acc[4], a47.x, w);
            FMA4(acc[5], a47.y, w);
            FMA4(acc[6], a47.z, w);
            FMA4(acc[7], a47.w, w);
        }
    }

    const float4 bs = *(const float4*)&bsc[cg*4];
    const float4 ws = *(const float4*)&Watt[cg*4];
    const float4 wd = *(const float4*)&Watt[EMB + cg*4];

    #pragma unroll
    for (int r = 0; r < 8; ++r) {
        float4 A = acc[r];
        A.x += bs.x; A.y += bs.y; A.z += bs.z; A.w += bs.w;
        const int row = r0 + rowb + r;

        if (row < NSEG) {
            uint2 pkt;
            pkt.x = f2bf(A.x) | (f2bf(A.y) << 16);
            pkt.y = f2bf(A.z) | (f2bf(A.w) << 16);
            ((uint2*)tab)[row * 32 + cg] = pkt;   // 8B, coalesced across cg
        }

        float ps = dot4(A, ws);
        float pd = dot4(A, wd);
        #pragma unroll
        for (int off = 16; off >= 1; off >>= 1) {  // reduce across 32-lane col group
            ps += __shfl_xor(ps, off);
            pd += __shfl_xor(pd, off);
        }
        if (cg == 0 && row < NSEG) { a_src[row] = ps; a_dst[row] = pd; }
    }
}

__device__ __forceinline__ float bf_lo(unsigned u) { return __uint_as_float(u << 16); }
__device__ __forceinline__ float bf_hi(unsigned u) { return __uint_as_float(u & 0xffff0000u); }
__device__ __forceinline__ float bcastf(float v, int j) {
    return __uint_as_float(__builtin_amdgcn_readlane(__float_as_uint(v), j));
}

// agg: one wave per segment; lane l owns features {2l, 2l+1} (one bf16x2 dword).
// Round-0 proven structure: per-chunk coalesced vector load of dst into
// registers, readlane broadcast for the 8-outstanding gather unroll.
__global__ __launch_bounds__(256) void agg_kernel(
    const int* __restrict__ dst, const float* __restrict__ a_src,
    const float* __restrict__ a_dst, const float* __restrict__ b_att,
    const int* __restrict__ seg_start, const unsigned int* __restrict__ tab32,
    float* __restrict__ out)
{
    const int wid = blockIdx.x * 4 + (threadIdx.x >> 6);
    if (wid >= NSEG) return;                 // wave-uniform exit
    const int lane = threadIdx.x & 63;
    const unsigned int* tabl = tab32 + lane; // row stride 64 dwords

    const int s0 = seg_start[wid];
    const int s1 = seg_start[wid + 1];
    const float aS = a_src[wid] + b_att[0];

    float accx = 0.f, accy = 0.f, ssum = 0.f;

    for (int cb = s0; cb < s1; cb += 64) {
        int n = s1 - cb; if (n > 64) n = 64;
        int e = cb + lane;
        int dmine = 0; float sc = 0.f;
        if (lane < n) {
            dmine = dst[e] << 6;             // pre-scaled dword row offset
            float att = aS + a_dst[dmine >> 6];
            att = att > 0.f ? att : 0.2f * att;   // leaky_relu 0.2
            sc  = expf(att - 1.f);
        }
        ssum += sc;

        int j = 0;
        for (; j + 7 < n; j += 8) {
            float w0 = bcastf(sc, j+0), w1 = bcastf(sc, j+1);
            float w2 = bcastf(sc, j+2), w3 = bcastf(sc, j+3);
            float w4 = bcastf(sc, j+4), w5 = bcastf(sc, j+5);
            float w6 = bcastf(sc, j+6), w7 = bcastf(sc, j+7);
            int d0 = __builtin_amdgcn_readlane(dmine, j+0);
            int d1 = __builtin_amdgcn_readlane(dmine, j+1);
            int d2 = __builtin_amdgcn_readlane(dmine, j+2);
            int d3 = __builtin_amdgcn_readlane(dmine, j+3);
            int d4 = __builtin_amdgcn_readlane(dmine, j+4);
            int d5 = __builtin_amdgcn_readlane(dmine, j+5);
            int d6 = __builtin_amdgcn_readlane(dmine, j+6);
            int d7 = __builtin_amdgcn_readlane(dmine, j+7);
            unsigned u0 = tabl[d0], u1 = tabl[d1], u2 = tabl[d2], u3 = tabl[d3];
            unsigned u4 = tabl[d4], u5 = tabl[d5], u6 = tabl[d6], u7 = tabl[d7];
            accx += w0 * bf_lo(u0); accy += w0 * bf_hi(u0);
            accx += w1 * bf_lo(u1); accy += w1 * bf_hi(u1);
            accx += w2 * bf_lo(u2); accy += w2 * bf_hi(u2);
            accx += w3 * bf_lo(u3); accy += w3 * bf_hi(u3);
            accx += w4 * bf_lo(u4); accy += w4 * bf_hi(u4);
            accx += w5 * bf_lo(u5); accy += w5 * bf_hi(u5);
            accx += w6 * bf_lo(u6); accy += w6 * bf_hi(u6);
            accx += w7 * bf_lo(u7); accy += w7 * bf_hi(u7);
        }
        for (; j < n; ++j) {
            float w = bcastf(sc, j);
            int   d = __builtin_amdgcn_readlane(dmine, j);
            unsigned u = tabl[d];
            accx += w * bf_lo(u);
            accy += w * bf_hi(u);
        }
    }

    #pragma unroll
    for (int off = 32; off >= 1; off >>= 1) ssum += __shfl_xor(ssum, off);

    const float inv = (s1 > s0) ? 1.f / ssum : 0.f;
    float ox = accx * inv, oy = accy * inv;
    ox = 1.f / (1.f + expf(-ox));
    oy = 1.f / (1.f + expf(-oy));
    *(float2*)&out[wid * EMB + 2 * lane] = make_float2(ox, oy);
}

extern "C" void kernel_launch(void* const* d_in, const int* in_sizes, int n_in,
                              void* d_out, int out_size, void* d_ws, size_t ws_size,
                              hipStream_t stream) {
    const float* emb  = (const float*)d_in[0];   // (20001, 128)
    const int*   edge = (const int*)  d_in[1];   // (640000, 2)
    const float* W    = (const float*)d_in[2];   // (128, 128)
    const float* bsc  = (const float*)d_in[3];   // (128,)
    const float* Watt = (const float*)d_in[4];   // (256,)
    const float* batt = (const float*)d_in[5];   // (1,)
    float* out = (float*)d_out;                  // (20001, 128)

    unsigned short* tab = (unsigned short*)d_ws;            // NSEG*EMB bf16 (5.12 MB)
    float* a_src = (float*)(tab + (size_t)NSEG * EMB);      // NSEG
    float* a_dst = a_src + NSEG;                            // NSEG
    int*   seg_start = (int*)(a_dst + NSEG);                // NSEG+1
    int*   dstc = seg_start + NSEG + 3;                     // NE (compacted dst col)

    prep_kernel<<<SCALE_BLOCKS + BOUNDS_BLOCKS, 256, 0, stream>>>(
        emb, W, bsc, Watt, edge, tab, a_src, a_dst, seg_start, dstc);
    agg_kernel<<<(NSEG + 3) / 4, 256, 0, stream>>>(
        dstc, a_src, a_dst, batt, seg_start, (const unsigned int*)tab, out);
}

// Round 4
// 107.567 us; speedup vs baseline: 1.0520x; 1.0520x over previous
//
#include <hip/hip_runtime.h>
#include <math.h>

#define NSEG 20001      // I_DIM + 1 segments / items
#define EMB  128
#define NE   640000

#define SCALE_BLOCKS 313         // ceil(NSEG/64) : 64 rows per block
#define BOUNDS_BLOCKS 2500       // NE/256 exact
#define APAD 136                 // bf16 elems per LDS A-row: 272B stride -> bank step 4, ~2-way max

typedef __attribute__((ext_vector_type(8))) short bf16x8;   // 8 bf16 = 4 VGPRs
typedef __attribute__((ext_vector_type(4))) float f32x4;    // MFMA C/D

__device__ __forceinline__ unsigned f2bf(float x) {
    unsigned u = __float_as_uint(x);
    return (u + 0x7fffu + ((u >> 16) & 1u)) >> 16;   // round-nearest-even bf16 bits
}
__device__ __forceinline__ float bfbits2f(unsigned h) { return __uint_as_float(h << 16); }

// One-shot: W (f32 [k][col]) -> wt_hi/wt_lo (bf16 [col][k], i.e. B^T[N][K] frag-ready).
// hi = bf16(x), lo = bf16(x - hi): 3-pass MFMA reconstructs f32-accurate product.
__global__ __launch_bounds__(256) void wconv_kernel(
    const float* __restrict__ W,
    unsigned short* __restrict__ wt_hi, unsigned short* __restrict__ wt_lo)
{
    const int c  = blockIdx.x * 8 + (threadIdx.x & 7);
    const int k0 = (threadIdx.x >> 3) * 4;
    unsigned h[4], l[4];
    #pragma unroll
    for (int i = 0; i < 4; ++i) {
        float x = W[(k0 + i) * EMB + c];
        h[i] = f2bf(x);
        l[i] = f2bf(x - bfbits2f(h[i]));
    }
    *(uint2*)&wt_hi[c * EMB + k0] = make_uint2(h[0] | (h[1] << 16), h[2] | (h[3] << 16));
    *(uint2*)&wt_lo[c * EMB + k0] = make_uint2(l[0] | (l[1] << 16), l[2] | (l[3] << 16));
}

// Fused prep:
//  blocks [0, SCALE_BLOCKS): item_scaled via 3-pass split-bf16 MFMA (16x16x32).
//    64 rows/block, 4 waves; wave w owns n-tiles {w, w+4} (cols c0=w*16+l15,
//    c1=c0+64 -> the tab bf16 pair (j, j+64) is lane-local). A = emb hi/lo in
//    padded LDS; B-frags read from wt_hi/wt_lo global (L2-hot, 20 MB total).
//    Verified layouts (m89/m91): A-frag A[M][K] bf16x8 @ [(lane&15)][(lane>>4)*8],
//    B-frag B^T[N][K] same pattern, C/D col=lane&15,row=(lane>>4)*4+reg.
//  blocks [SCALE_BLOCKS, +BOUNDS_BLOCKS): segment bounds + dst compaction.
__global__ __launch_bounds__(256) void prep_kernel(
    const float* __restrict__ emb,
    const unsigned short* __restrict__ wt_hi, const unsigned short* __restrict__ wt_lo,
    const float* __restrict__ bsc, const float* __restrict__ Watt,
    const int* __restrict__ edge,
    unsigned short* __restrict__ tab,       // bf16 tab: dword j of row = feats (j, j+64)
    float* __restrict__ a_src, float* __restrict__ a_dst,
    int* __restrict__ seg_start, int* __restrict__ dst)
{
    const int tid = threadIdx.x;
    if (blockIdx.x >= SCALE_BLOCKS) {
        // ---- bounds + dst-compaction ----
        int e = (blockIdx.x - SCALE_BLOCKS) * 256 + tid;
        int2 p = ((const int2*)edge)[e];            // coalesced 8B
        dst[e] = p.y;
        int sp = __shfl_up(p.x, 1);
        if ((tid & 63) == 0) sp = (e == 0) ? -1 : edge[2*e - 2];
        for (int t = sp + 1; t <= p.x; ++t) seg_start[t] = e;
        if (e == NE - 1) {
            for (int t = p.x + 1; t <= NSEG; ++t) seg_start[t] = NE;
        }
        return;
    }

    // ---- scale branch: MFMA ----
    __shared__ unsigned short Ah[64 * APAD];   // 17.0 KB
    __shared__ unsigned short Al[64 * APAD];   // 17.0 KB
    __shared__ float ps_part[4][64];
    __shared__ float pd_part[4][64];           // total ~36 KB -> 4 blocks/CU

    const int r0   = blockIdx.x * 64;
    const int w    = tid >> 6;          // wave id: n-tiles {w, w+4}
    const int lane = tid & 63;
    const int l15  = lane & 15;
    const int lk   = lane >> 4;

    // emb tile -> bf16 hi/lo in LDS (padded row-major [64][APAD])
    const float4* embg4 = (const float4*)emb;
    const int gmax = NSEG * 32 - 1;
    #pragma unroll
    for (int j = 0; j < 8; ++j) {
        int idx = tid + j * 256;            // 0..2047 float4 slots
        int row = idx >> 5, f4 = idx & 31;
        int g = r0 * 32 + idx;
        float4 v = embg4[g <= gmax ? g : gmax];
        unsigned h0 = f2bf(v.x), h1 = f2bf(v.y), h2 = f2bf(v.z), h3 = f2bf(v.w);
        unsigned l0 = f2bf(v.x - bfbits2f(h0)), l1 = f2bf(v.y - bfbits2f(h1));
        unsigned l2 = f2bf(v.z - bfbits2f(h2)), l3 = f2bf(v.w - bfbits2f(h3));
        int o = row * APAD + f4 * 4;
        *(uint2*)&Ah[o] = make_uint2(h0 | (h1 << 16), h2 | (h3 << 16));
        *(uint2*)&Al[o] = make_uint2(l0 | (l1 << 16), l2 | (l3 << 16));
    }
    __syncthreads();

    const int c0 = w * 16 + l15;        // n-tile w
    const int c1 = c0 + 64;             // n-tile w+4
    const bf16x8* Bh0p = (const bf16x8*)&wt_hi[c0 * EMB];
    const bf16x8* Bh1p = (const bf16x8*)&wt_hi[c1 * EMB];
    const bf16x8* Bl0p = (const bf16x8*)&wt_lo[c0 * EMB];
    const bf16x8* Bl1p = (const bf16x8*)&wt_lo[c1 * EMB];

    f32x4 acc[4][2];
    #pragma unroll
    for (int m = 0; m < 4; ++m) {
        acc[m][0] = (f32x4){0.f, 0.f, 0.f, 0.f};
        acc[m][1] = (f32x4){0.f, 0.f, 0.f, 0.f};
    }

    #pragma unroll
    for (int kt = 0; kt < 4; ++kt) {
        const int fo = kt * 4 + lk;                 // bf16x8 index into [col][128]
        bf16x8 Bh0 = Bh0p[fo], Bh1 = Bh1p[fo];
        bf16x8 Bl0 = Bl0p[fo], Bl1 = Bl1p[fo];
        #pragma unroll
        for (int m = 0; m < 4; ++m) {
            const int ao = (m * 16 + l15) * APAD + kt * 32 + lk * 8;
            bf16x8 Af = *(const bf16x8*)&Ah[ao];
            bf16x8 Lf = *(const bf16x8*)&Al[ao];
            acc[m][0] = __builtin_amdgcn_mfma_f32_16x16x32_bf16(Af, Bh0, acc[m][0], 0, 0, 0);
            acc[m][1] = __builtin_amdgcn_mfma_f32_16x16x32_bf16(Af, Bh1, acc[m][1], 0, 0, 0);
            acc[m][0] = __builtin_amdgcn_mfma_f32_16x16x32_bf16(Lf, Bh0, acc[m][0], 0, 0, 0);
            acc[m][1] = __builtin_amdgcn_mfma_f32_16x16x32_bf16(Lf, Bh1, acc[m][1], 0, 0, 0);
            acc[m][0] = __builtin_amdgcn_mfma_f32_16x16x32_bf16(Af, Bl0, acc[m][0], 0, 0, 0);
            acc[m][1] = __builtin_amdgcn_mfma_f32_16x16x32_bf16(Af, Bl1, acc[m][1], 0, 0, 0);
        }
    }

    // epilogue: bias, tab pack (feat c0 | feat c0+64), att dots + cross-wave sum
    const float bs0 = bsc[c0],        bs1 = bsc[c1];
    const float ws0 = Watt[c0],       ws1 = Watt[c1];
    const float wd0 = Watt[EMB + c0], wd1 = Watt[EMB + c1];

    #pragma unroll
    for (int m = 0; m < 4; ++m) {
        #pragma unroll
        for (int r = 0; r < 4; ++r) {
            float v0 = acc[m][0][r] + bs0;
            float v1 = acc[m][1][r] + bs1;
            const int rl  = m * 16 + lk * 4 + r;     // local row (C/D layout)
            const int row = r0 + rl;
            if (row < NSEG)
                ((unsigned*)tab)[row * 64 + c0] = f2bf(v0) | (f2bf(v1) << 16);
            float ps = v0 * ws0 + v1 * ws1;
            float pd = v0 * wd0 + v1 * wd1;
            #pragma unroll
            for (int off = 8; off >= 1; off >>= 1) {  // reduce 16 cols per group
                ps += __shfl_xor(ps, off);
                pd += __shfl_xor(pd, off);
            }
            if (l15 == 0) { ps_part[w][rl] = ps; pd_part[w][rl] = pd; }
        }
    }
    __syncthreads();
    if (tid < 64) {
        const int row = r0 + tid;
        if (row < NSEG) {
            a_src[row] = ps_part[0][tid] + ps_part[1][tid] + ps_part[2][tid] + ps_part[3][tid];
            a_dst[row] = pd_part[0][tid] + pd_part[1][tid] + pd_part[2][tid] + pd_part[3][tid];
        }
    }
}

__device__ __forceinline__ float bf_lo(unsigned u) { return __uint_as_float(u << 16); }
__device__ __forceinline__ float bf_hi(unsigned u) { return __uint_as_float(u & 0xffff0000u); }
__device__ __forceinline__ float bcastf(float v, int j) {
    return __uint_as_float(__builtin_amdgcn_readlane(__float_as_uint(v), j));
}

// agg: one wave per segment; lane l owns features {l, l+64} (one bf16x2 dword,
// matching the new tab packing). Round-0 proven gather structure otherwise.
__global__ __launch_bounds__(256) void agg_kernel(
    const int* __restrict__ dst, const float* __restrict__ a_src,
    const float* __restrict__ a_dst, const float* __restrict__ b_att,
    const int* __restrict__ seg_start, const unsigned int* __restrict__ tab32,
    float* __restrict__ out)
{
    const int wid = blockIdx.x * 4 + (threadIdx.x >> 6);
    if (wid >= NSEG) return;                 // wave-uniform exit
    const int lane = threadIdx.x & 63;
    const unsigned int* tabl = tab32 + lane; // row stride 64 dwords

    const int s0 = seg_start[wid];
    const int s1 = seg_start[wid + 1];
    const float aS = a_src[wid] + b_att[0];

    float accx = 0.f, accy = 0.f, ssum = 0.f;

    for (int cb = s0; cb < s1; cb += 64) {
        int n = s1 - cb; if (n > 64) n = 64;
        int e = cb + lane;
        int dmine = 0; float sc = 0.f;
        if (lane < n) {
            dmine = dst[e] << 6;             // pre-scaled dword row offset
            float att = aS + a_dst[dmine >> 6];
            att = att > 0.f ? att : 0.2f * att;   // leaky_relu 0.2
            sc  = expf(att - 1.f);
        }
        ssum += sc;

        int j = 0;
        for (; j + 7 < n; j += 8) {
            float w0 = bcastf(sc, j+0), w1 = bcastf(sc, j+1);
            float w2 = bcastf(sc, j+2), w3 = bcastf(sc, j+3);
            float w4 = bcastf(sc, j+4), w5 = bcastf(sc, j+5);
            float w6 = bcastf(sc, j+6), w7 = bcastf(sc, j+7);
            int d0 = __builtin_amdgcn_readlane(dmine, j+0);
            int d1 = __builtin_amdgcn_readlane(dmine, j+1);
            int d2 = __builtin_amdgcn_readlane(dmine, j+2);
            int d3 = __builtin_amdgcn_readlane(dmine, j+3);
            int d4 = __builtin_amdgcn_readlane(dmine, j+4);
            int d5 = __builtin_amdgcn_readlane(dmine, j+5);
            int d6 = __builtin_amdgcn_readlane(dmine, j+6);
            int d7 = __builtin_amdgcn_readlane(dmine, j+7);
            unsigned u0 = tabl[d0], u1 = tabl[d1], u2 = tabl[d2], u3 = tabl[d3];
            unsigned u4 = tabl[d4], u5 = tabl[d5], u6 = tabl[d6], u7 = tabl[d7];
            accx += w0 * bf_lo(u0); accy += w0 * bf_hi(u0);
            accx += w1 * bf_lo(u1); accy += w1 * bf_hi(u1);
            accx += w2 * bf_lo(u2); accy += w2 * bf_hi(u2);
            accx += w3 * bf_lo(u3); accy += w3 * bf_hi(u3);
            accx += w4 * bf_lo(u4); accy += w4 * bf_hi(u4);
            accx += w5 * bf_lo(u5); accy += w5 * bf_hi(u5);
            accx += w6 * bf_lo(u6); accy += w6 * bf_hi(u6);
            accx += w7 * bf_lo(u7); accy += w7 * bf_hi(u7);
        }
        for (; j < n; ++j) {
            float w = bcastf(sc, j);
            int   d = __builtin_amdgcn_readlane(dmine, j);
            unsigned u = tabl[d];
            accx += w * bf_lo(u);
            accy += w * bf_hi(u);
        }
    }

    #pragma unroll
    for (int off = 32; off >= 1; off >>= 1) ssum += __shfl_xor(ssum, off);

    const float inv = (s1 > s0) ? 1.f / ssum : 0.f;
    float ox = accx * inv, oy = accy * inv;
    ox = 1.f / (1.f + expf(-ox));
    oy = 1.f / (1.f + expf(-oy));
    out[wid * EMB + lane]      = ox;   // feat lane
    out[wid * EMB + 64 + lane] = oy;   // feat lane+64
}

extern "C" void kernel_launch(void* const* d_in, const int* in_sizes, int n_in,
                              void* d_out, int out_size, void* d_ws, size_t ws_size,
                              hipStream_t stream) {
    const float* emb  = (const float*)d_in[0];   // (20001, 128)
    const int*   edge = (const int*)  d_in[1];   // (640000, 2)
    const float* W    = (const float*)d_in[2];   // (128, 128)
    const float* bsc  = (const float*)d_in[3];   // (128,)
    const float* Watt = (const float*)d_in[4];   // (256,)
    const float* batt = (const float*)d_in[5];   // (1,)
    float* out = (float*)d_out;                  // (20001, 128)

    unsigned short* tab = (unsigned short*)d_ws;            // NSEG*EMB bf16 (5.12 MB)
    float* a_src = (float*)(tab + (size_t)NSEG * EMB);      // NSEG
    float* a_dst = a_src + NSEG;                            // NSEG
    int*   seg_start = (int*)(a_dst + NSEG);                // NSEG+1
    int*   dstc = seg_start + NSEG + 3;                     // NE (compacted dst col)
    unsigned short* wt_hi = (unsigned short*)((char*)d_ws + (32u << 20));  // 32 KB, 16B-aligned
    unsigned short* wt_lo = wt_hi + EMB * EMB;                             // 32 KB

    wconv_kernel<<<16, 256, 0, stream>>>(W, wt_hi, wt_lo);
    prep_kernel<<<SCALE_BLOCKS + BOUNDS_BLOCKS, 256, 0, stream>>>(
        emb, wt_hi, wt_lo, bsc, Watt, edge, tab, a_src, a_dst, seg_start, dstc);
    agg_kernel<<<(NSEG + 3) / 4, 256, 0, stream>>>(
        dstc, a_src, a_dst, batt, seg_start, (const unsigned int*)tab, out);
}